// Round 7
// baseline (988.871 us; speedup 1.0000x reference)
//
#include <hip/hip_runtime.h>
#include <hip/hip_bf16.h>
#include <math.h>

// MFGN forward, MI355X. One block (512 thr, 8 waves) per outfit.
// fac running state: fp32 in REGISTERS (lane(q,n16)@wave wid holds
// fac[item=q*4+rr][f][col=wid*16+n16], 16 VGPRs) + bf16 LDS mirror facB
// (MFMA A-operand). Mirror re-rounded from fp32 each update -> no compounding
// (R6 lesson: bf16 running state broke com 113 vs 2.94).
// feat state bf16 (scores tolerant). com G=F F^T computed from fp32 regs at
// end of Phase B into comG. LDS ~41.5KB -> 3 blocks/CU at launch_bounds(512,6).

typedef __attribute__((ext_vector_type(8))) short short8;
typedef __attribute__((ext_vector_type(4))) float f32x4;

#define MFMA16(a, b, c) __builtin_amdgcn_mfma_f32_16x16x32_bf16(a, b, c, 0, 0, 0)

__device__ __forceinline__ float lrelu(float x) { return x > 0.0f ? x : 0.01f * x; }

__device__ __forceinline__ ushort f2bf(float f) {
  unsigned u = __builtin_bit_cast(unsigned, f);
  u += 0x7fffu + ((u >> 16) & 1u);  // RNE
  return (ushort)(u >> 16);
}
__device__ __forceinline__ float bflo(unsigned u) {
  return __builtin_bit_cast(float, u << 16);
}
__device__ __forceinline__ float bfhi(unsigned u) {
  return __builtin_bit_cast(float, u & 0xffff0000u);
}
__device__ __forceinline__ unsigned pk2(float a, float b) {
  float2 t; t.x = a; t.y = b;
  __hip_bfloat162 h = __float22bfloat162_rn(t);
  unsigned u;
  __builtin_memcpy(&u, &h, 4);
  return u;
}
__device__ __forceinline__ short8 load_bfrag(const float* __restrict__ W, int ldn,
                                             int kbase, int col) {
  short8 r;
#pragma unroll
  for (int j = 0; j < 8; ++j) r[j] = (short)f2bf(W[(kbase + j) * ldn + col]);
  return r;
}

__global__ void zero_com(float* out) { if (threadIdx.x == 0) out[2048] = 0.0f; }

__global__ __launch_bounds__(512, 6) void mfgn_kernel(
    const int* __restrict__ outfit_items,
    const float* __restrict__ items_feature,
    const int* __restrict__ items_neighbor,
    const float* __restrict__ cfW1, const float* __restrict__ cfb1,
    const float* __restrict__ cfW2, const float* __restrict__ cfb2,
    const float* __restrict__ f2fW1, const float* __restrict__ f2fb1,
    const float* __restrict__ f2fW2, const float* __restrict__ f2fb2,
    const float* __restrict__ f2iW1, const float* __restrict__ f2ib1,
    const float* __restrict__ f2iW2, const float* __restrict__ f2ib2,
    const float* __restrict__ i2iW1, const float* __restrict__ i2ib1,
    const float* __restrict__ i2iW2, const float* __restrict__ i2ib2,
    const float* __restrict__ o2sW, const float* __restrict__ o2sb,
    float* __restrict__ out)
{
  __shared__ ushort facB[64 * 136] __attribute__((aligned(16)));  // 17408 B bf16 mirror
  __shared__ ushort featB[16 * 136] __attribute__((aligned(16))); //  4352 B bf16 state
  __shared__ ushort stg[64 * 136] __attribute__((aligned(16)));   // 17408 B products/hid
  __shared__ float comG[256];                                     //  1024 B fp32 G sums
  __shared__ float redE[8];
  __shared__ int oiL[16];
  __shared__ int clAll[256];
  __shared__ int ncAll[16];
  __shared__ int vslL[16];
  __shared__ int refcntL[16];
  __shared__ int nvsL;

  const int o = blockIdx.x;
  const int tid = (int)threadIdx.x;
  const int lane = tid & 63;
  const int wid = tid >> 6;        // wave owns output cols wid*16..+15
  const int n16 = lane & 15;
  const int q = lane >> 4;
  const int kb = q * 8;
  const int col = wid * 16 + n16;

  // ---------------- load inputs ----------------
  if (tid < 16) oiL[tid] = outfit_items[o * 16 + tid];
  if (tid < 256) comG[tid] = 0.0f;
  {
    const int n = tid >> 5, d0 = (tid & 31) * 4;
    float4 v = *(const float4*)(items_feature + o * 2048 + tid * 4);
    uint2 pk; pk.x = pk2(v.x, v.y); pk.y = pk2(v.z, v.w);
    *(uint2*)(featB + n * 136 + d0) = pk;
  }
  if (tid == 0) {
    int cnt = 0;
    for (int s = 0; s < 16; ++s) refcntL[s] = 0;
    for (int s = 0; s < 16; ++s) {
      int v = oiL[s];
      if (v != -1) { vslL[cnt++] = s; refcntL[v]++; }
    }
    nvsL = cnt;
  }
  for (int s = wid; s < 16; s += 8) {
    const int iv = outfit_items[o * 16 + s];
    if (iv == -1) { if (lane == 0) ncAll[s] = 0; continue; }
    int cand = -1;
    if (lane < 24) cand = (lane < 16) ? outfit_items[o * 16 + lane]
                                      : items_neighbor[o * 128 + iv * 8 + (lane - 16)];
    bool ok = (lane < 24) && (cand != -1) && (cand != iv);
    unsigned long long bm = __ballot(ok);
    if (ok) clAll[s * 16 + __popcll(bm & ((1ull << lane) - 1ull))] = cand;
    if (lane == 0) ncAll[s] = (int)__popcll(bm);
  }
  __syncthreads();
  const int nvs = nvsL;

  // ---------------- Phase A: creat_factors ----------------
  {
    const int f = wid & 3, half = wid >> 2;
    short8 wA[2][4];
#pragma unroll
    for (int etl = 0; etl < 2; ++etl)
#pragma unroll
      for (int kt = 0; kt < 4; ++kt)
        wA[etl][kt] = load_bfrag(cfW1 + f * 8192, 64, kt * 32 + kb, (half * 2 + etl) * 16 + n16);
    f32x4 acc[2];
    acc[0] = (f32x4){0.f,0.f,0.f,0.f}; acc[1] = (f32x4){0.f,0.f,0.f,0.f};
    for (int kt = 0; kt < 4; ++kt) {
      short8 x = *(const short8*)(featB + n16 * 136 + kt * 32 + kb);
      acc[0] = MFMA16(wA[0][kt], x, acc[0]);
      acc[1] = MFMA16(wA[1][kt], x, acc[1]);
    }
#pragma unroll
    for (int etl = 0; etl < 2; ++etl) {
      f32x4 b1q = *(const f32x4*)(cfb1 + f * 64 + (half * 2 + etl) * 16 + q * 4);
      float h0 = lrelu(acc[etl][0] + b1q[0]), h1 = lrelu(acc[etl][1] + b1q[1]);
      float h2 = lrelu(acc[etl][2] + b1q[2]), h3 = lrelu(acc[etl][3] + b1q[3]);
      uint2 pk; pk.x = pk2(h0, h1); pk.y = pk2(h2, h3);
      *(uint2*)(stg + (f * 16 + n16) * 136 + (half * 2 + etl) * 16 + q * 4) = pk;
    }
    __syncthreads();
    short8 wB[4][2];
#pragma unroll
    for (int ctl = 0; ctl < 4; ++ctl)
#pragma unroll
      for (int kt = 0; kt < 2; ++kt)
        wB[ctl][kt] = load_bfrag(cfW2 + f * 8192, 128, kt * 32 + kb, half * 64 + ctl * 16 + n16);
    f32x4 acc2[4];
#pragma unroll
    for (int ctl = 0; ctl < 4; ++ctl) acc2[ctl] = (f32x4){0.f,0.f,0.f,0.f};
    for (int kt = 0; kt < 2; ++kt) {
      short8 h = *(const short8*)(stg + (f * 16 + n16) * 136 + kt * 32 + kb);
#pragma unroll
      for (int ctl = 0; ctl < 4; ++ctl) acc2[ctl] = MFMA16(h, wB[ctl][kt], acc2[ctl]);
    }
#pragma unroll
    for (int ctl = 0; ctl < 4; ++ctl) {
      int c = half * 64 + ctl * 16 + n16;
      float b2 = cfb2[f * 128 + c];
#pragma unroll
      for (int r = 0; r < 4; ++r)
        facB[((q * 4 + r) * 4 + f) * 136 + c] = f2bf(lrelu(acc2[ctl][r] + b2));
    }
    __syncthreads();
  }

  // ---------------- Phase B: inter_factors (fp32 state in registers) ----------------
  {
    short8 w1f[4], w2f[4];
#pragma unroll
    for (int kt = 0; kt < 4; ++kt) {
      w1f[kt] = load_bfrag(f2fW1, 128, kt * 32 + kb, col);
      w2f[kt] = load_bfrag(f2fW2, 128, kt * 32 + kb, col);
    }
    const f32x4 b1q = *(const f32x4*)(f2fb1 + wid * 16 + q * 4);
    const float b2v = f2fb2[col];
    // fp32 running fac: fac32[rr*4+f] = fac[item=q*4+rr][f][col]
    float fac32[16];
#pragma unroll
    for (int rr = 0; rr < 4; ++rr)
#pragma unroll
      for (int f = 0; f < 4; ++f)
        fac32[rr * 4 + f] = bflo((unsigned)facB[((q * 4 + rr) * 4 + f) * 136 + col]);

    const int rS = tid >> 3, kcS = tid & 7;
    const int fS = rS & 3, ciS = rS >> 2;
    const int kcol = kcS * 16;

    for (int s = 0; s < 16; ++s) {
      const int iv = oiL[s];
      if (iv == -1) continue;
      const int nc = ncAll[s];
      const int mtn = (nc + 3) >> 2;
      // stage stg[r=ci*4+f][k] = bf16(fac[iv][f][k] * fac[cand][f][k]) from mirror
      if (ciS < nc) {
        const int cit = clAll[s * 16 + ciS];
        const ushort* tp = facB + (iv * 4 + fS) * 136 + kcol;
        const ushort* cp = facB + (cit * 4 + fS) * 136 + kcol;
        uint4 ta = *(const uint4*)tp, tb = *(const uint4*)(tp + 8);
        uint4 ca = *(const uint4*)cp, cb = *(const uint4*)(cp + 8);
        uint4 u0, u1;
        u0.x = pk2(bflo(ta.x) * bflo(ca.x), bfhi(ta.x) * bfhi(ca.x));
        u0.y = pk2(bflo(ta.y) * bflo(ca.y), bfhi(ta.y) * bfhi(ca.y));
        u0.z = pk2(bflo(ta.z) * bflo(ca.z), bfhi(ta.z) * bfhi(ca.z));
        u0.w = pk2(bflo(ta.w) * bflo(ca.w), bfhi(ta.w) * bfhi(ca.w));
        u1.x = pk2(bflo(tb.x) * bflo(cb.x), bfhi(tb.x) * bfhi(cb.x));
        u1.y = pk2(bflo(tb.y) * bflo(cb.y), bfhi(tb.y) * bfhi(cb.y));
        u1.z = pk2(bflo(tb.z) * bflo(cb.z), bfhi(tb.z) * bfhi(cb.z));
        u1.w = pk2(bflo(tb.w) * bflo(cb.w), bfhi(tb.w) * bfhi(cb.w));
        *(uint4*)(stg + rS * 136 + kcol) = u0;
        *(uint4*)(stg + rS * 136 + kcol + 8) = u1;
      } else {
        uint4 z; z.x = z.y = z.z = z.w = 0;
        *(uint4*)(stg + rS * 136 + kcol) = z;
        *(uint4*)(stg + rS * 136 + kcol + 8) = z;
      }
      __syncthreads();
      // L1 swapped: H[row][e=col block]
      f32x4 acc[4];
#pragma unroll
      for (int mt = 0; mt < 4; ++mt) acc[mt] = (f32x4){0.f,0.f,0.f,0.f};
      for (int kt = 0; kt < 4; ++kt)
#pragma unroll
        for (int mt = 0; mt < 4; ++mt)
          if (mt < mtn) {
            short8 x = *(const short8*)(stg + (mt * 16 + n16) * 136 + kt * 32 + kb);
            acc[mt] = MFMA16(w1f[kt], x, acc[mt]);
          }
      __syncthreads();  // products consumed (stg about to become hid)
#pragma unroll
      for (int mt = 0; mt < 4; ++mt)
        if (mt < mtn) {
          float h0 = lrelu(acc[mt][0] + b1q[0]), h1 = lrelu(acc[mt][1] + b1q[1]);
          float h2 = lrelu(acc[mt][2] + b1q[2]), h3 = lrelu(acc[mt][3] + b1q[3]);
          uint2 pk; pk.x = pk2(h0, h1); pk.y = pk2(h2, h3);
          *(uint2*)(stg + (mt * 16 + n16) * 136 + wid * 16 + q * 4) = pk;
        }
      __syncthreads();  // hid ready
      f32x4 acc2[4];
#pragma unroll
      for (int mt = 0; mt < 4; ++mt) acc2[mt] = (f32x4){0.f,0.f,0.f,0.f};
      for (int kt = 0; kt < 4; ++kt)
#pragma unroll
        for (int mt = 0; mt < 4; ++mt)
          if (mt < mtn) {
            short8 h = *(const short8*)(stg + (mt * 16 + n16) * 136 + kt * 32 + kb);
            acc2[mt] = MFMA16(h, w2f[kt], acc2[mt]);
          }
      // epilogue: rows ci*4+f (f=reg); mask ci=mt*4+q<nc; sum over ci; bcast over q
      float part[4] = {0.f, 0.f, 0.f, 0.f};
#pragma unroll
      for (int mt = 0; mt < 4; ++mt) {
        bool act = (mt * 4 + q) < nc;
        if (act)
#pragma unroll
          for (int r = 0; r < 4; ++r) part[r] += lrelu(acc2[mt][r] + b2v);
      }
#pragma unroll
      for (int r = 0; r < 4; ++r) {
        float v = part[r];
        v += __shfl_xor(v, 16);
        v += __shfl_xor(v, 32);
        part[r] = v;  // all q-lanes now hold total
      }
      if (q == (iv >> 2)) {  // owning q-group: fp32 update + refresh mirror
        const int rr = iv & 3;
#pragma unroll
        for (int f = 0; f < 4; ++f) {
          fac32[rr * 4 + f] += part[f];
          facB[(iv * 4 + f) * 136 + col] = f2bf(fac32[rr * 4 + f]);
        }
      }
      __syncthreads();
    }

    // fp32 G = F F^T accumulation for com (per item, over this lane's col)
#pragma unroll
    for (int rr = 0; rr < 4; ++rr)
#pragma unroll
      for (int f = 0; f < 4; ++f)
#pragma unroll
        for (int g = 0; g < 4; ++g) {
          float p = fac32[rr * 4 + f] * fac32[rr * 4 + g];
          p += __shfl_xor(p, 1);
          p += __shfl_xor(p, 2);
          p += __shfl_xor(p, 4);
          p += __shfl_xor(p, 8);
          if (n16 == 0) atomicAdd(&comG[(q * 4 + rr) * 16 + f * 4 + g], p);
        }
  }

  // ---------------- Phase C: infer_items (facB mirror IS the A operand) ----------------
  {
    short8 w1f[4], w2f[4];
#pragma unroll
    for (int kt = 0; kt < 4; ++kt) {
      w1f[kt] = load_bfrag(f2iW1, 128, kt * 32 + kb, col);
      w2f[kt] = load_bfrag(f2iW2, 128, kt * 32 + kb, col);
    }
    const f32x4 b1q = *(const f32x4*)(f2ib1 + wid * 16 + q * 4);
    const float b2v = f2ib2[col];
    f32x4 acc[4];
#pragma unroll
    for (int mt = 0; mt < 4; ++mt) acc[mt] = (f32x4){0.f,0.f,0.f,0.f};
    for (int kt = 0; kt < 4; ++kt)
#pragma unroll
      for (int mt = 0; mt < 4; ++mt) {
        short8 x = *(const short8*)(facB + (mt * 16 + n16) * 136 + kt * 32 + kb);
        acc[mt] = MFMA16(w1f[kt], x, acc[mt]);
      }
#pragma unroll
    for (int mt = 0; mt < 4; ++mt) {
      float h0 = lrelu(acc[mt][0] + b1q[0]), h1 = lrelu(acc[mt][1] + b1q[1]);
      float h2 = lrelu(acc[mt][2] + b1q[2]), h3 = lrelu(acc[mt][3] + b1q[3]);
      uint2 pk; pk.x = pk2(h0, h1); pk.y = pk2(h2, h3);
      *(uint2*)(stg + (mt * 16 + n16) * 136 + wid * 16 + q * 4) = pk;
    }
    __syncthreads();
    f32x4 acc2[4];
#pragma unroll
    for (int mt = 0; mt < 4; ++mt) acc2[mt] = (f32x4){0.f,0.f,0.f,0.f};
    for (int kt = 0; kt < 4; ++kt)
#pragma unroll
      for (int mt = 0; mt < 4; ++mt) {
        short8 h = *(const short8*)(stg + (mt * 16 + n16) * 136 + kt * 32 + kb);
        acc2[mt] = MFMA16(h, w2f[kt], acc2[mt]);
      }
#pragma unroll
    for (int mt = 0; mt < 4; ++mt) {
      int item = mt * 4 + q;
      float g = 0.f;
#pragma unroll
      for (int r = 0; r < 4; ++r) g += lrelu(acc2[mt][r] + b2v);
      int a = item * 136 + col;  // unique (item,col) per lane
      featB[a] = f2bf(bflo((unsigned)featB[a]) + (float)refcntL[item] * g);
    }
    __syncthreads();
  }

  // ---------------- Phase D: inter_items (featB IS the A operand) ----------------
  {
    short8 w1f[4], w2f[4];
#pragma unroll
    for (int kt = 0; kt < 4; ++kt) {
      w1f[kt] = load_bfrag(i2iW1, 128, kt * 32 + kb, col);
      w2f[kt] = load_bfrag(i2iW2, 128, kt * 32 + kb, col);
    }
    const f32x4 b1q = *(const f32x4*)(i2ib1 + wid * 16 + q * 4);
    const float b2v = i2ib2[col];

    for (int u = 0; u < nvs; ++u) {
      const int iv = oiL[vslL[u]];
      f32x4 acc = (f32x4){0.f,0.f,0.f,0.f};
      for (int kt = 0; kt < 4; ++kt) {
        short8 x = *(const short8*)(featB + n16 * 136 + kt * 32 + kb);
        acc = MFMA16(w1f[kt], x, acc);
      }
      {
        float h0 = lrelu(acc[0] + b1q[0]), h1 = lrelu(acc[1] + b1q[1]);
        float h2 = lrelu(acc[2] + b1q[2]), h3 = lrelu(acc[3] + b1q[3]);
        uint2 pk; pk.x = pk2(h0, h1); pk.y = pk2(h2, h3);
        *(uint2*)(stg + n16 * 136 + wid * 16 + q * 4) = pk;
      }
      __syncthreads();
      f32x4 acc2 = (f32x4){0.f,0.f,0.f,0.f};
      for (int kt = 0; kt < 4; ++kt) {
        short8 h = *(const short8*)(stg + n16 * 136 + kt * 32 + kb);
        acc2 = MFMA16(h, w2f[kt], acc2);
      }
      float part = 0.f;
#pragma unroll
      for (int r = 0; r < 4; ++r) {
        int item = q * 4 + r;
        float w = (item == iv) ? 0.0f : (float)refcntL[item];
        part += w * lrelu(acc2[r] + b2v);
      }
      part += __shfl_xor(part, 16);
      part += __shfl_xor(part, 32);
      if (q == 0) {
        int a = iv * 136 + col;
        featB[a] = f2bf(bflo((unsigned)featB[a]) + part);
      }
      __syncthreads();
    }
  }

  // ---------------- Phase E: infer_outfit + score ----------------
  if (tid < 128) {
    float sum = 0.0f;
    for (int u = 0; u < nvs; ++u)
      sum += bflo((unsigned)featB[oiL[vslL[u]] * 136 + tid]);
    float v = sum * o2sW[tid];
#pragma unroll
    for (int off = 1; off < 64; off <<= 1) v += __shfl_xor(v, off);
    if (lane == 0) redE[wid] = v;
  }
  __syncthreads();
  if (tid == 0) {
    float t = redE[0] + redE[1] + o2sb[0];
    out[o] = 1.0f / (1.0f + expf(-t));
  }

  // ---------------- Phase F: finalize com from fp32 comG ----------------
  __syncthreads();  // E's redE read complete; comG atomics long since drained
  {
    float sq = 0.0f;
    if (tid < 256) {
      int n = tid >> 4, f = (tid >> 2) & 3, g = tid & 3;
      float v = comG[tid] - ((f == g) ? 1.0f : 0.0f);
      sq = (oiL[n] != -1) ? v * v : 0.0f;
#pragma unroll
      for (int off = 1; off < 64; off <<= 1) sq += __shfl_xor(sq, off);
      if (lane == 0) redE[wid] = sq;
    }
    __syncthreads();
    if (tid == 0) {
      float tot = redE[0] + redE[1] + redE[2] + redE[3];
      atomicAdd(out + 2048, tot * (1.0f / 2048.0f));
    }
  }
}

extern "C" void kernel_launch(void* const* d_in, const int* in_sizes, int n_in,
                              void* d_out, int out_size, void* d_ws, size_t ws_size,
                              hipStream_t stream) {
  float* out = (float*)d_out;
  hipLaunchKernelGGL(zero_com, dim3(1), dim3(64), 0, stream, out);
  hipLaunchKernelGGL(mfgn_kernel, dim3(2048), dim3(512), 0, stream,
                     (const int*)d_in[0],
                     (const float*)d_in[1],
                     (const int*)d_in[2],
                     // d_in[3] items_factors unused (overwritten by creat_factors)
                     (const float*)d_in[4], (const float*)d_in[5],
                     (const float*)d_in[6], (const float*)d_in[7],
                     (const float*)d_in[8], (const float*)d_in[9],
                     (const float*)d_in[10], (const float*)d_in[11],
                     (const float*)d_in[12], (const float*)d_in[13],
                     (const float*)d_in[14], (const float*)d_in[15],
                     (const float*)d_in[16], (const float*)d_in[17],
                     (const float*)d_in[18], (const float*)d_in[19],
                     (const float*)d_in[20], (const float*)d_in[21],
                     out);
}

// Round 8
// 564.654 us; speedup vs baseline: 1.7513x; 1.7513x over previous
//
#include <hip/hip_runtime.h>
#include <hip/hip_bf16.h>
#include <math.h>

// MFGN forward, MI355X. One block (512 thr, 8 waves) per outfit.
// fac running state: fp32 in REGISTERS (lane(q,n16)@wave wid holds
// fac[item=q*4+rr][f][col=wid*16+n16], 16 VGPRs) + bf16 LDS mirror facB
// (MFMA A-operand). Mirror re-rounded from fp32 each update -> no compounding.
// feat state bf16. com G=F F^T computed from fp32 regs at end of Phase B.
// __launch_bounds__(512,4): R7 lesson — (512,6)'s ~85-VGPR cap made LLVM
// rematerialize weight-fragment gathers in-loop (VGPR=40, FETCH 903MB, 925us).
// Cap 128 keeps w1f/w2f/fac32 register-resident (R5 behavior: VGPR=64, 11.5MB).

typedef __attribute__((ext_vector_type(8))) short short8;
typedef __attribute__((ext_vector_type(4))) float f32x4;

#define MFMA16(a, b, c) __builtin_amdgcn_mfma_f32_16x16x32_bf16(a, b, c, 0, 0, 0)

__device__ __forceinline__ float lrelu(float x) { return x > 0.0f ? x : 0.01f * x; }

__device__ __forceinline__ ushort f2bf(float f) {
  unsigned u = __builtin_bit_cast(unsigned, f);
  u += 0x7fffu + ((u >> 16) & 1u);  // RNE
  return (ushort)(u >> 16);
}
__device__ __forceinline__ float bflo(unsigned u) {
  return __builtin_bit_cast(float, u << 16);
}
__device__ __forceinline__ float bfhi(unsigned u) {
  return __builtin_bit_cast(float, u & 0xffff0000u);
}
__device__ __forceinline__ unsigned pk2(float a, float b) {
  float2 t; t.x = a; t.y = b;
  __hip_bfloat162 h = __float22bfloat162_rn(t);
  unsigned u;
  __builtin_memcpy(&u, &h, 4);
  return u;
}
__device__ __forceinline__ short8 load_bfrag(const float* __restrict__ W, int ldn,
                                             int kbase, int col) {
  short8 r;
#pragma unroll
  for (int j = 0; j < 8; ++j) r[j] = (short)f2bf(W[(kbase + j) * ldn + col]);
  return r;
}

__global__ void zero_com(float* out) { if (threadIdx.x == 0) out[2048] = 0.0f; }

__global__ __launch_bounds__(512, 4) void mfgn_kernel(
    const int* __restrict__ outfit_items,
    const float* __restrict__ items_feature,
    const int* __restrict__ items_neighbor,
    const float* __restrict__ cfW1, const float* __restrict__ cfb1,
    const float* __restrict__ cfW2, const float* __restrict__ cfb2,
    const float* __restrict__ f2fW1, const float* __restrict__ f2fb1,
    const float* __restrict__ f2fW2, const float* __restrict__ f2fb2,
    const float* __restrict__ f2iW1, const float* __restrict__ f2ib1,
    const float* __restrict__ f2iW2, const float* __restrict__ f2ib2,
    const float* __restrict__ i2iW1, const float* __restrict__ i2ib1,
    const float* __restrict__ i2iW2, const float* __restrict__ i2ib2,
    const float* __restrict__ o2sW, const float* __restrict__ o2sb,
    float* __restrict__ out)
{
  __shared__ ushort facB[64 * 136] __attribute__((aligned(16)));  // 17408 B bf16 mirror
  __shared__ ushort featB[16 * 136] __attribute__((aligned(16))); //  4352 B bf16 state
  __shared__ ushort stg[64 * 136] __attribute__((aligned(16)));   // 17408 B products/hid
  __shared__ float comG[256];                                     //  1024 B fp32 G sums
  __shared__ float redE[8];
  __shared__ int oiL[16];
  __shared__ int clAll[256];
  __shared__ int ncAll[16];
  __shared__ int vslL[16];
  __shared__ int refcntL[16];
  __shared__ int nvsL;

  const int o = blockIdx.x;
  const int tid = (int)threadIdx.x;
  const int lane = tid & 63;
  const int wid = tid >> 6;        // wave owns output cols wid*16..+15
  const int n16 = lane & 15;
  const int q = lane >> 4;
  const int kb = q * 8;
  const int col = wid * 16 + n16;

  // ---------------- load inputs ----------------
  if (tid < 16) oiL[tid] = outfit_items[o * 16 + tid];
  if (tid < 256) comG[tid] = 0.0f;
  {
    const int n = tid >> 5, d0 = (tid & 31) * 4;
    float4 v = *(const float4*)(items_feature + o * 2048 + tid * 4);
    uint2 pk; pk.x = pk2(v.x, v.y); pk.y = pk2(v.z, v.w);
    *(uint2*)(featB + n * 136 + d0) = pk;
  }
  if (tid == 0) {
    int cnt = 0;
    for (int s = 0; s < 16; ++s) refcntL[s] = 0;
    for (int s = 0; s < 16; ++s) {
      int v = oiL[s];
      if (v != -1) { vslL[cnt++] = s; refcntL[v]++; }
    }
    nvsL = cnt;
  }
  for (int s = wid; s < 16; s += 8) {
    const int iv = outfit_items[o * 16 + s];
    if (iv == -1) { if (lane == 0) ncAll[s] = 0; continue; }
    int cand = -1;
    if (lane < 24) cand = (lane < 16) ? outfit_items[o * 16 + lane]
                                      : items_neighbor[o * 128 + iv * 8 + (lane - 16)];
    bool ok = (lane < 24) && (cand != -1) && (cand != iv);
    unsigned long long bm = __ballot(ok);
    if (ok) clAll[s * 16 + __popcll(bm & ((1ull << lane) - 1ull))] = cand;
    if (lane == 0) ncAll[s] = (int)__popcll(bm);
  }
  __syncthreads();
  const int nvs = nvsL;

  // ---------------- Phase A: creat_factors ----------------
  {
    const int f = wid & 3, half = wid >> 2;
    short8 wA[2][4];
#pragma unroll
    for (int etl = 0; etl < 2; ++etl)
#pragma unroll
      for (int kt = 0; kt < 4; ++kt)
        wA[etl][kt] = load_bfrag(cfW1 + f * 8192, 64, kt * 32 + kb, (half * 2 + etl) * 16 + n16);
    f32x4 acc[2];
    acc[0] = (f32x4){0.f,0.f,0.f,0.f}; acc[1] = (f32x4){0.f,0.f,0.f,0.f};
    for (int kt = 0; kt < 4; ++kt) {
      short8 x = *(const short8*)(featB + n16 * 136 + kt * 32 + kb);
      acc[0] = MFMA16(wA[0][kt], x, acc[0]);
      acc[1] = MFMA16(wA[1][kt], x, acc[1]);
    }
#pragma unroll
    for (int etl = 0; etl < 2; ++etl) {
      f32x4 b1q = *(const f32x4*)(cfb1 + f * 64 + (half * 2 + etl) * 16 + q * 4);
      float h0 = lrelu(acc[etl][0] + b1q[0]), h1 = lrelu(acc[etl][1] + b1q[1]);
      float h2 = lrelu(acc[etl][2] + b1q[2]), h3 = lrelu(acc[etl][3] + b1q[3]);
      uint2 pk; pk.x = pk2(h0, h1); pk.y = pk2(h2, h3);
      *(uint2*)(stg + (f * 16 + n16) * 136 + (half * 2 + etl) * 16 + q * 4) = pk;
    }
    __syncthreads();
    short8 wB[4][2];
#pragma unroll
    for (int ctl = 0; ctl < 4; ++ctl)
#pragma unroll
      for (int kt = 0; kt < 2; ++kt)
        wB[ctl][kt] = load_bfrag(cfW2 + f * 8192, 128, kt * 32 + kb, half * 64 + ctl * 16 + n16);
    f32x4 acc2[4];
#pragma unroll
    for (int ctl = 0; ctl < 4; ++ctl) acc2[ctl] = (f32x4){0.f,0.f,0.f,0.f};
    for (int kt = 0; kt < 2; ++kt) {
      short8 h = *(const short8*)(stg + (f * 16 + n16) * 136 + kt * 32 + kb);
#pragma unroll
      for (int ctl = 0; ctl < 4; ++ctl) acc2[ctl] = MFMA16(h, wB[ctl][kt], acc2[ctl]);
    }
#pragma unroll
    for (int ctl = 0; ctl < 4; ++ctl) {
      int c = half * 64 + ctl * 16 + n16;
      float b2 = cfb2[f * 128 + c];
#pragma unroll
      for (int r = 0; r < 4; ++r)
        facB[((q * 4 + r) * 4 + f) * 136 + c] = f2bf(lrelu(acc2[ctl][r] + b2));
    }
    __syncthreads();
  }

  // ---------------- Phase B: inter_factors (fp32 state in registers) ----------------
  {
    short8 w1f[4], w2f[4];
#pragma unroll
    for (int kt = 0; kt < 4; ++kt) {
      w1f[kt] = load_bfrag(f2fW1, 128, kt * 32 + kb, col);
      w2f[kt] = load_bfrag(f2fW2, 128, kt * 32 + kb, col);
    }
    const f32x4 b1q = *(const f32x4*)(f2fb1 + wid * 16 + q * 4);
    const float b2v = f2fb2[col];
    // fp32 running fac: fac32[rr*4+f] = fac[item=q*4+rr][f][col]
    float fac32[16];
#pragma unroll
    for (int rr = 0; rr < 4; ++rr)
#pragma unroll
      for (int f = 0; f < 4; ++f)
        fac32[rr * 4 + f] = bflo((unsigned)facB[((q * 4 + rr) * 4 + f) * 136 + col]);

    const int rS = tid >> 3, kcS = tid & 7;
    const int fS = rS & 3, ciS = rS >> 2;
    const int kcol = kcS * 16;

    for (int s = 0; s < 16; ++s) {
      const int iv = oiL[s];
      if (iv == -1) continue;
      const int nc = ncAll[s];
      const int mtn = (nc + 3) >> 2;
      // stage stg[r=ci*4+f][k] = bf16(fac[iv][f][k] * fac[cand][f][k]) from mirror
      if (ciS < nc) {
        const int cit = clAll[s * 16 + ciS];
        const ushort* tp = facB + (iv * 4 + fS) * 136 + kcol;
        const ushort* cp = facB + (cit * 4 + fS) * 136 + kcol;
        uint4 ta = *(const uint4*)tp, tb = *(const uint4*)(tp + 8);
        uint4 ca = *(const uint4*)cp, cb = *(const uint4*)(cp + 8);
        uint4 u0, u1;
        u0.x = pk2(bflo(ta.x) * bflo(ca.x), bfhi(ta.x) * bfhi(ca.x));
        u0.y = pk2(bflo(ta.y) * bflo(ca.y), bfhi(ta.y) * bfhi(ca.y));
        u0.z = pk2(bflo(ta.z) * bflo(ca.z), bfhi(ta.z) * bfhi(ca.z));
        u0.w = pk2(bflo(ta.w) * bflo(ca.w), bfhi(ta.w) * bfhi(ca.w));
        u1.x = pk2(bflo(tb.x) * bflo(cb.x), bfhi(tb.x) * bfhi(cb.x));
        u1.y = pk2(bflo(tb.y) * bflo(cb.y), bfhi(tb.y) * bfhi(cb.y));
        u1.z = pk2(bflo(tb.z) * bflo(cb.z), bfhi(tb.z) * bfhi(cb.z));
        u1.w = pk2(bflo(tb.w) * bflo(cb.w), bfhi(tb.w) * bfhi(cb.w));
        *(uint4*)(stg + rS * 136 + kcol) = u0;
        *(uint4*)(stg + rS * 136 + kcol + 8) = u1;
      } else {
        uint4 z; z.x = z.y = z.z = z.w = 0;
        *(uint4*)(stg + rS * 136 + kcol) = z;
        *(uint4*)(stg + rS * 136 + kcol + 8) = z;
      }
      __syncthreads();
      // L1 swapped: H[row][e=col block]
      f32x4 acc[4];
#pragma unroll
      for (int mt = 0; mt < 4; ++mt) acc[mt] = (f32x4){0.f,0.f,0.f,0.f};
      for (int kt = 0; kt < 4; ++kt)
#pragma unroll
        for (int mt = 0; mt < 4; ++mt)
          if (mt < mtn) {
            short8 x = *(const short8*)(stg + (mt * 16 + n16) * 136 + kt * 32 + kb);
            acc[mt] = MFMA16(w1f[kt], x, acc[mt]);
          }
      __syncthreads();  // products consumed (stg about to become hid)
#pragma unroll
      for (int mt = 0; mt < 4; ++mt)
        if (mt < mtn) {
          float h0 = lrelu(acc[mt][0] + b1q[0]), h1 = lrelu(acc[mt][1] + b1q[1]);
          float h2 = lrelu(acc[mt][2] + b1q[2]), h3 = lrelu(acc[mt][3] + b1q[3]);
          uint2 pk; pk.x = pk2(h0, h1); pk.y = pk2(h2, h3);
          *(uint2*)(stg + (mt * 16 + n16) * 136 + wid * 16 + q * 4) = pk;
        }
      __syncthreads();  // hid ready
      f32x4 acc2[4];
#pragma unroll
      for (int mt = 0; mt < 4; ++mt) acc2[mt] = (f32x4){0.f,0.f,0.f,0.f};
      for (int kt = 0; kt < 4; ++kt)
#pragma unroll
        for (int mt = 0; mt < 4; ++mt)
          if (mt < mtn) {
            short8 h = *(const short8*)(stg + (mt * 16 + n16) * 136 + kt * 32 + kb);
            acc2[mt] = MFMA16(h, w2f[kt], acc2[mt]);
          }
      // epilogue: rows ci*4+f (f=reg); mask ci=mt*4+q<nc; sum over ci; bcast over q
      float part[4] = {0.f, 0.f, 0.f, 0.f};
#pragma unroll
      for (int mt = 0; mt < 4; ++mt) {
        bool act = (mt * 4 + q) < nc;
        if (act)
#pragma unroll
          for (int r = 0; r < 4; ++r) part[r] += lrelu(acc2[mt][r] + b2v);
      }
#pragma unroll
      for (int r = 0; r < 4; ++r) {
        float v = part[r];
        v += __shfl_xor(v, 16);
        v += __shfl_xor(v, 32);
        part[r] = v;  // all q-lanes now hold total
      }
      if (q == (iv >> 2)) {  // owning q-group: fp32 update + refresh mirror
        const int rr = iv & 3;
#pragma unroll
        for (int f = 0; f < 4; ++f) {
          fac32[rr * 4 + f] += part[f];
          facB[(iv * 4 + f) * 136 + col] = f2bf(fac32[rr * 4 + f]);
        }
      }
      __syncthreads();
    }

    // fp32 G = F F^T accumulation for com (per item, over this lane's col)
#pragma unroll
    for (int rr = 0; rr < 4; ++rr)
#pragma unroll
      for (int f = 0; f < 4; ++f)
#pragma unroll
        for (int g = 0; g < 4; ++g) {
          float p = fac32[rr * 4 + f] * fac32[rr * 4 + g];
          p += __shfl_xor(p, 1);
          p += __shfl_xor(p, 2);
          p += __shfl_xor(p, 4);
          p += __shfl_xor(p, 8);
          if (n16 == 0) atomicAdd(&comG[(q * 4 + rr) * 16 + f * 4 + g], p);
        }
  }

  // ---------------- Phase C: infer_items (facB mirror IS the A operand) ----------------
  {
    short8 w1f[4], w2f[4];
#pragma unroll
    for (int kt = 0; kt < 4; ++kt) {
      w1f[kt] = load_bfrag(f2iW1, 128, kt * 32 + kb, col);
      w2f[kt] = load_bfrag(f2iW2, 128, kt * 32 + kb, col);
    }
    const f32x4 b1q = *(const f32x4*)(f2ib1 + wid * 16 + q * 4);
    const float b2v = f2ib2[col];
    f32x4 acc[4];
#pragma unroll
    for (int mt = 0; mt < 4; ++mt) acc[mt] = (f32x4){0.f,0.f,0.f,0.f};
    for (int kt = 0; kt < 4; ++kt)
#pragma unroll
      for (int mt = 0; mt < 4; ++mt) {
        short8 x = *(const short8*)(facB + (mt * 16 + n16) * 136 + kt * 32 + kb);
        acc[mt] = MFMA16(w1f[kt], x, acc[mt]);
      }
#pragma unroll
    for (int mt = 0; mt < 4; ++mt) {
      float h0 = lrelu(acc[mt][0] + b1q[0]), h1 = lrelu(acc[mt][1] + b1q[1]);
      float h2 = lrelu(acc[mt][2] + b1q[2]), h3 = lrelu(acc[mt][3] + b1q[3]);
      uint2 pk; pk.x = pk2(h0, h1); pk.y = pk2(h2, h3);
      *(uint2*)(stg + (mt * 16 + n16) * 136 + wid * 16 + q * 4) = pk;
    }
    __syncthreads();
    f32x4 acc2[4];
#pragma unroll
    for (int mt = 0; mt < 4; ++mt) acc2[mt] = (f32x4){0.f,0.f,0.f,0.f};
    for (int kt = 0; kt < 4; ++kt)
#pragma unroll
      for (int mt = 0; mt < 4; ++mt) {
        short8 h = *(const short8*)(stg + (mt * 16 + n16) * 136 + kt * 32 + kb);
        acc2[mt] = MFMA16(h, w2f[kt], acc2[mt]);
      }
#pragma unroll
    for (int mt = 0; mt < 4; ++mt) {
      int item = mt * 4 + q;
      float g = 0.f;
#pragma unroll
      for (int r = 0; r < 4; ++r) g += lrelu(acc2[mt][r] + b2v);
      int a = item * 136 + col;  // unique (item,col) per lane
      featB[a] = f2bf(bflo((unsigned)featB[a]) + (float)refcntL[item] * g);
    }
    __syncthreads();
  }

  // ---------------- Phase D: inter_items (featB IS the A operand) ----------------
  {
    short8 w1f[4], w2f[4];
#pragma unroll
    for (int kt = 0; kt < 4; ++kt) {
      w1f[kt] = load_bfrag(i2iW1, 128, kt * 32 + kb, col);
      w2f[kt] = load_bfrag(i2iW2, 128, kt * 32 + kb, col);
    }
    const f32x4 b1q = *(const f32x4*)(i2ib1 + wid * 16 + q * 4);
    const float b2v = i2ib2[col];

    for (int u = 0; u < nvs; ++u) {
      const int iv = oiL[vslL[u]];
      f32x4 acc = (f32x4){0.f,0.f,0.f,0.f};
      for (int kt = 0; kt < 4; ++kt) {
        short8 x = *(const short8*)(featB + n16 * 136 + kt * 32 + kb);
        acc = MFMA16(w1f[kt], x, acc);
      }
      {
        float h0 = lrelu(acc[0] + b1q[0]), h1 = lrelu(acc[1] + b1q[1]);
        float h2 = lrelu(acc[2] + b1q[2]), h3 = lrelu(acc[3] + b1q[3]);
        uint2 pk; pk.x = pk2(h0, h1); pk.y = pk2(h2, h3);
        *(uint2*)(stg + n16 * 136 + wid * 16 + q * 4) = pk;
      }
      __syncthreads();
      f32x4 acc2 = (f32x4){0.f,0.f,0.f,0.f};
      for (int kt = 0; kt < 4; ++kt) {
        short8 h = *(const short8*)(stg + n16 * 136 + kt * 32 + kb);
        acc2 = MFMA16(h, w2f[kt], acc2);
      }
      float part = 0.f;
#pragma unroll
      for (int r = 0; r < 4; ++r) {
        int item = q * 4 + r;
        float w = (item == iv) ? 0.0f : (float)refcntL[item];
        part += w * lrelu(acc2[r] + b2v);
      }
      part += __shfl_xor(part, 16);
      part += __shfl_xor(part, 32);
      if (q == 0) {
        int a = iv * 136 + col;
        featB[a] = f2bf(bflo((unsigned)featB[a]) + part);
      }
      __syncthreads();
    }
  }

  // ---------------- Phase E: infer_outfit + score ----------------
  if (tid < 128) {
    float sum = 0.0f;
    for (int u = 0; u < nvs; ++u)
      sum += bflo((unsigned)featB[oiL[vslL[u]] * 136 + tid]);
    float v = sum * o2sW[tid];
#pragma unroll
    for (int off = 1; off < 64; off <<= 1) v += __shfl_xor(v, off);
    if (lane == 0) redE[wid] = v;
  }
  __syncthreads();
  if (tid == 0) {
    float t = redE[0] + redE[1] + o2sb[0];
    out[o] = 1.0f / (1.0f + expf(-t));
  }

  // ---------------- Phase F: finalize com from fp32 comG ----------------
  __syncthreads();  // E's redE read complete; comG atomics long since drained
  {
    float sq = 0.0f;
    if (tid < 256) {
      int n = tid >> 4, f = (tid >> 2) & 3, g = tid & 3;
      float v = comG[tid] - ((f == g) ? 1.0f : 0.0f);
      sq = (oiL[n] != -1) ? v * v : 0.0f;
#pragma unroll
      for (int off = 1; off < 64; off <<= 1) sq += __shfl_xor(sq, off);
      if (lane == 0) redE[wid] = sq;
    }
    __syncthreads();
    if (tid == 0) {
      float tot = redE[0] + redE[1] + redE[2] + redE[3];
      atomicAdd(out + 2048, tot * (1.0f / 2048.0f));
    }
  }
}

extern "C" void kernel_launch(void* const* d_in, const int* in_sizes, int n_in,
                              void* d_out, int out_size, void* d_ws, size_t ws_size,
                              hipStream_t stream) {
  float* out = (float*)d_out;
  hipLaunchKernelGGL(zero_com, dim3(1), dim3(64), 0, stream, out);
  hipLaunchKernelGGL(mfgn_kernel, dim3(2048), dim3(512), 0, stream,
                     (const int*)d_in[0],
                     (const float*)d_in[1],
                     (const int*)d_in[2],
                     // d_in[3] items_factors unused (overwritten by creat_factors)
                     (const float*)d_in[4], (const float*)d_in[5],
                     (const float*)d_in[6], (const float*)d_in[7],
                     (const float*)d_in[8], (const float*)d_in[9],
                     (const float*)d_in[10], (const float*)d_in[11],
                     (const float*)d_in[12], (const float*)d_in[13],
                     (const float*)d_in[14], (const float*)d_in[15],
                     (const float*)d_in[16], (const float*)d_in[17],
                     (const float*)d_in[18], (const float*)d_in[19],
                     (const float*)d_in[20], (const float*)d_in[21],
                     out);
}

// Round 9
// 464.709 us; speedup vs baseline: 2.1279x; 1.2151x over previous
//
#include <hip/hip_runtime.h>
#include <hip/hip_bf16.h>
#include <math.h>

// MFGN forward, MI355X. One block (512 thr, 8 waves) per outfit.
// R5 register budget restored (fp32 facL in LDS; NO per-lane fac32 regs —
// R8 lesson: +16 live VGPRs in Phase B tips the unified VGPR/AGPR file into
// scratch spill, 151MB WRITE). LDS-side wins kept: featB bf16 in MFMA A-layout
// (Phase D fully destaged), separate prod/hid buffers (B: 3 barriers/step).
// com computed from fp32 facL in Phase F (R5 numerics, absmax 0.0117).

typedef __attribute__((ext_vector_type(8))) short short8;
typedef __attribute__((ext_vector_type(4))) float f32x4;

#define MFMA16(a, b, c) __builtin_amdgcn_mfma_f32_16x16x32_bf16(a, b, c, 0, 0, 0)

__device__ __forceinline__ float lrelu(float x) { return x > 0.0f ? x : 0.01f * x; }

__device__ __forceinline__ ushort f2bf(float f) {
  unsigned u = __builtin_bit_cast(unsigned, f);
  u += 0x7fffu + ((u >> 16) & 1u);  // RNE
  return (ushort)(u >> 16);
}
__device__ __forceinline__ float bflo(unsigned u) {
  return __builtin_bit_cast(float, u << 16);
}
__device__ __forceinline__ unsigned pk2(float a, float b) {
  float2 t; t.x = a; t.y = b;
  __hip_bfloat162 h = __float22bfloat162_rn(t);
  unsigned u;
  __builtin_memcpy(&u, &h, 4);
  return u;
}
__device__ __forceinline__ short8 load_bfrag(const float* __restrict__ W, int ldn,
                                             int kbase, int col) {
  short8 r;
#pragma unroll
  for (int j = 0; j < 8; ++j) r[j] = (short)f2bf(W[(kbase + j) * ldn + col]);
  return r;
}

__global__ void zero_com(float* out) { if (threadIdx.x == 0) out[2048] = 0.0f; }

__global__ __launch_bounds__(512, 4) void mfgn_kernel(
    const int* __restrict__ outfit_items,
    const float* __restrict__ items_feature,
    const int* __restrict__ items_neighbor,
    const float* __restrict__ cfW1, const float* __restrict__ cfb1,
    const float* __restrict__ cfW2, const float* __restrict__ cfb2,
    const float* __restrict__ f2fW1, const float* __restrict__ f2fb1,
    const float* __restrict__ f2fW2, const float* __restrict__ f2fb2,
    const float* __restrict__ f2iW1, const float* __restrict__ f2ib1,
    const float* __restrict__ f2iW2, const float* __restrict__ f2ib2,
    const float* __restrict__ i2iW1, const float* __restrict__ i2ib1,
    const float* __restrict__ i2iW2, const float* __restrict__ i2ib2,
    const float* __restrict__ o2sW, const float* __restrict__ o2sb,
    float* __restrict__ out)
{
  __shared__ float facL[16 * 528];                                 // 33792 B fp32 state
  __shared__ ushort prodS[64 * 136] __attribute__((aligned(16)));  // 17408 B bf16 A-staging
  __shared__ ushort hidS[64 * 136] __attribute__((aligned(16)));   // 17408 B bf16 hidden
  __shared__ ushort featB[16 * 136] __attribute__((aligned(16)));  //  4352 B bf16 feat state
  __shared__ float redE[8];
  __shared__ int oiL[16];
  __shared__ int clAll[256];
  __shared__ int ncAll[16];
  __shared__ int vslL[16];
  __shared__ int refcntL[16];
  __shared__ int nvsL;

  const int o = blockIdx.x;
  const int tid = (int)threadIdx.x;
  const int lane = tid & 63;
  const int wid = tid >> 6;        // wave owns output cols wid*16..+15
  const int n16 = lane & 15;
  const int q = lane >> 4;
  const int kb = q * 8;
  const int col = wid * 16 + n16;

  // ---------------- load inputs ----------------
  if (tid < 16) oiL[tid] = outfit_items[o * 16 + tid];
  {
    const int n = tid >> 5, d0 = (tid & 31) * 4;
    float4 v = *(const float4*)(items_feature + o * 2048 + tid * 4);
    uint2 pk; pk.x = pk2(v.x, v.y); pk.y = pk2(v.z, v.w);
    *(uint2*)(featB + n * 136 + d0) = pk;
  }
  if (tid == 0) {
    int cnt = 0;
    for (int s = 0; s < 16; ++s) refcntL[s] = 0;
    for (int s = 0; s < 16; ++s) {
      int v = oiL[s];
      if (v != -1) { vslL[cnt++] = s; refcntL[v]++; }
    }
    nvsL = cnt;
  }
  for (int s = wid; s < 16; s += 8) {
    const int iv = outfit_items[o * 16 + s];
    if (iv == -1) { if (lane == 0) ncAll[s] = 0; continue; }
    int cand = -1;
    if (lane < 24) cand = (lane < 16) ? outfit_items[o * 16 + lane]
                                      : items_neighbor[o * 128 + iv * 8 + (lane - 16)];
    bool ok = (lane < 24) && (cand != -1) && (cand != iv);
    unsigned long long bm = __ballot(ok);
    if (ok) clAll[s * 16 + __popcll(bm & ((1ull << lane) - 1ull))] = cand;
    if (lane == 0) ncAll[s] = (int)__popcll(bm);
  }
  __syncthreads();
  const int nvs = nvsL;

  // ---------------- Phase A: creat_factors ----------------
  {
    const int f = wid & 3, half = wid >> 2;
    short8 wA[2][4];
#pragma unroll
    for (int etl = 0; etl < 2; ++etl)
#pragma unroll
      for (int kt = 0; kt < 4; ++kt)
        wA[etl][kt] = load_bfrag(cfW1 + f * 8192, 64, kt * 32 + kb, (half * 2 + etl) * 16 + n16);
    f32x4 acc[2];
    acc[0] = (f32x4){0.f,0.f,0.f,0.f}; acc[1] = (f32x4){0.f,0.f,0.f,0.f};
    for (int kt = 0; kt < 4; ++kt) {
      short8 x = *(const short8*)(featB + n16 * 136 + kt * 32 + kb);
      acc[0] = MFMA16(wA[0][kt], x, acc[0]);
      acc[1] = MFMA16(wA[1][kt], x, acc[1]);
    }
#pragma unroll
    for (int etl = 0; etl < 2; ++etl) {
      f32x4 b1q = *(const f32x4*)(cfb1 + f * 64 + (half * 2 + etl) * 16 + q * 4);
      float h0 = lrelu(acc[etl][0] + b1q[0]), h1 = lrelu(acc[etl][1] + b1q[1]);
      float h2 = lrelu(acc[etl][2] + b1q[2]), h3 = lrelu(acc[etl][3] + b1q[3]);
      uint2 pk; pk.x = pk2(h0, h1); pk.y = pk2(h2, h3);
      *(uint2*)(hidS + (f * 16 + n16) * 136 + (half * 2 + etl) * 16 + q * 4) = pk;
    }
    __syncthreads();
    short8 wB[4][2];
#pragma unroll
    for (int ctl = 0; ctl < 4; ++ctl)
#pragma unroll
      for (int kt = 0; kt < 2; ++kt)
        wB[ctl][kt] = load_bfrag(cfW2 + f * 8192, 128, kt * 32 + kb, half * 64 + ctl * 16 + n16);
    f32x4 acc2[4];
#pragma unroll
    for (int ctl = 0; ctl < 4; ++ctl) acc2[ctl] = (f32x4){0.f,0.f,0.f,0.f};
    for (int kt = 0; kt < 2; ++kt) {
      short8 h = *(const short8*)(hidS + (f * 16 + n16) * 136 + kt * 32 + kb);
#pragma unroll
      for (int ctl = 0; ctl < 4; ++ctl) acc2[ctl] = MFMA16(h, wB[ctl][kt], acc2[ctl]);
    }
#pragma unroll
    for (int ctl = 0; ctl < 4; ++ctl) {
      int c = half * 64 + ctl * 16 + n16;
      float b2 = cfb2[f * 128 + c];
#pragma unroll
      for (int r = 0; r < 4; ++r)
        facL[(q * 4 + r) * 528 + f * 132 + c] = lrelu(acc2[ctl][r] + b2);
    }
    __syncthreads();
  }

  // ---------------- Phase B: inter_factors (fp32 facL state) ----------------
  {
    short8 w1f[4], w2f[4];
#pragma unroll
    for (int kt = 0; kt < 4; ++kt) {
      w1f[kt] = load_bfrag(f2fW1, 128, kt * 32 + kb, col);
      w2f[kt] = load_bfrag(f2fW2, 128, kt * 32 + kb, col);
    }
    const f32x4 b1q = *(const f32x4*)(f2fb1 + wid * 16 + q * 4);
    const float b2v = f2fb2[col];
    const int rS = tid >> 3, kcS = tid & 7;   // staging: row, 16-value k-chunk
    const int fS = rS & 3, ciS = rS >> 2;
    const int k0 = kcS * 16;

    for (int s = 0; s < 16; ++s) {
      const int iv = oiL[s];
      if (iv == -1) continue;
      const int nc = ncAll[s];
      const int mtn = (nc + 3) >> 2;
      // stage prod[r=ci*4+f][k] = bf16(fac[iv][f][k] * fac[cand][f][k])
      if (ciS < nc) {
        const int cit = clAll[s * 16 + ciS];
        const float* tp = facL + iv * 528 + fS * 132;
        const float* cp = facL + cit * 528 + fS * 132;
#pragma unroll
        for (int i2 = 0; i2 < 2; ++i2) {
          const int k = k0 + i2 * 8;
          float4 a0 = *(const float4*)(tp + k), a1 = *(const float4*)(tp + k + 4);
          float4 c0 = *(const float4*)(cp + k), c1 = *(const float4*)(cp + k + 4);
          uint4 u;
          u.x = pk2(a0.x * c0.x, a0.y * c0.y); u.y = pk2(a0.z * c0.z, a0.w * c0.w);
          u.z = pk2(a1.x * c1.x, a1.y * c1.y); u.w = pk2(a1.z * c1.z, a1.w * c1.w);
          *(uint4*)(prodS + rS * 136 + k) = u;
        }
      } else {
        uint4 z; z.x = z.y = z.z = z.w = 0;
        *(uint4*)(prodS + rS * 136 + k0) = z;
        *(uint4*)(prodS + rS * 136 + k0 + 8) = z;
      }
      __syncthreads();  // [b1] products ready
      // L1 swapped: lane -> H[row=mt*16+n16][e=wid*16+q*4+reg]; write hidS (own slice)
      f32x4 acc[4];
#pragma unroll
      for (int mt = 0; mt < 4; ++mt) acc[mt] = (f32x4){0.f,0.f,0.f,0.f};
      for (int kt = 0; kt < 4; ++kt)
#pragma unroll
        for (int mt = 0; mt < 4; ++mt)
          if (mt < mtn) {
            short8 x = *(const short8*)(prodS + (mt * 16 + n16) * 136 + kt * 32 + kb);
            acc[mt] = MFMA16(w1f[kt], x, acc[mt]);
          }
#pragma unroll
      for (int mt = 0; mt < 4; ++mt)
        if (mt < mtn) {
          float h0 = lrelu(acc[mt][0] + b1q[0]), h1 = lrelu(acc[mt][1] + b1q[1]);
          float h2 = lrelu(acc[mt][2] + b1q[2]), h3 = lrelu(acc[mt][3] + b1q[3]);
          uint2 pk; pk.x = pk2(h0, h1); pk.y = pk2(h2, h3);
          *(uint2*)(hidS + (mt * 16 + n16) * 136 + wid * 16 + q * 4) = pk;
        }
      __syncthreads();  // [b2] hid ready
      // L2 normal: lane -> Y[r=mt*16+q*4+reg][c=col]
      f32x4 acc2[4];
#pragma unroll
      for (int mt = 0; mt < 4; ++mt) acc2[mt] = (f32x4){0.f,0.f,0.f,0.f};
      for (int kt = 0; kt < 4; ++kt)
#pragma unroll
        for (int mt = 0; mt < 4; ++mt)
          if (mt < mtn) {
            short8 h = *(const short8*)(hidS + (mt * 16 + n16) * 136 + kt * 32 + kb);
            acc2[mt] = MFMA16(h, w2f[kt], acc2[mt]);
          }
      // epilogue: rows ci*4+f (f=reg); mask ci=mt*4+q<nc; sum over ci
      float part[4] = {0.f, 0.f, 0.f, 0.f};
#pragma unroll
      for (int mt = 0; mt < 4; ++mt) {
        bool act = (mt * 4 + q) < nc;
        if (act)
#pragma unroll
          for (int r = 0; r < 4; ++r) part[r] += lrelu(acc2[mt][r] + b2v);
      }
#pragma unroll
      for (int r = 0; r < 4; ++r) {
        float v = part[r];
        v += __shfl_xor(v, 16);
        v += __shfl_xor(v, 32);
        part[r] = v;
      }
      if (q == 0) {  // wave owns cols exclusively -> plain fp32 +=
#pragma unroll
        for (int r = 0; r < 4; ++r)
          facL[iv * 528 + r * 132 + col] += part[r];
      }
      __syncthreads();  // [b3] facL updated for next step's stage
    }
  }

  // ---------------- Phase C: infer_items ----------------
  {
    short8 w1f[4], w2f[4];
#pragma unroll
    for (int kt = 0; kt < 4; ++kt) {
      w1f[kt] = load_bfrag(f2iW1, 128, kt * 32 + kb, col);
      w2f[kt] = load_bfrag(f2iW2, 128, kt * 32 + kb, col);
    }
    const f32x4 b1q = *(const f32x4*)(f2ib1 + wid * 16 + q * 4);
    const float b2v = f2ib2[col];
    // stage prod[r=item*4+f][k] = bf16(fac[item][f][k])
    {
      const int r = tid >> 3, kc = tid & 7, k0 = kc * 16;
      const int f = r & 3, item = r >> 2;
      const float* sp = facL + item * 528 + f * 132;
#pragma unroll
      for (int i2 = 0; i2 < 2; ++i2) {
        const int k = k0 + i2 * 8;
        float4 a0 = *(const float4*)(sp + k), a1 = *(const float4*)(sp + k + 4);
        uint4 u;
        u.x = pk2(a0.x, a0.y); u.y = pk2(a0.z, a0.w);
        u.z = pk2(a1.x, a1.y); u.w = pk2(a1.z, a1.w);
        *(uint4*)(prodS + r * 136 + k) = u;
      }
    }
    __syncthreads();
    f32x4 acc[4];
#pragma unroll
    for (int mt = 0; mt < 4; ++mt) acc[mt] = (f32x4){0.f,0.f,0.f,0.f};
    for (int kt = 0; kt < 4; ++kt)
#pragma unroll
      for (int mt = 0; mt < 4; ++mt) {
        short8 x = *(const short8*)(prodS + (mt * 16 + n16) * 136 + kt * 32 + kb);
        acc[mt] = MFMA16(w1f[kt], x, acc[mt]);
      }
#pragma unroll
    for (int mt = 0; mt < 4; ++mt) {
      float h0 = lrelu(acc[mt][0] + b1q[0]), h1 = lrelu(acc[mt][1] + b1q[1]);
      float h2 = lrelu(acc[mt][2] + b1q[2]), h3 = lrelu(acc[mt][3] + b1q[3]);
      uint2 pk; pk.x = pk2(h0, h1); pk.y = pk2(h2, h3);
      *(uint2*)(hidS + (mt * 16 + n16) * 136 + wid * 16 + q * 4) = pk;
    }
    __syncthreads();
    f32x4 acc2[4];
#pragma unroll
    for (int mt = 0; mt < 4; ++mt) acc2[mt] = (f32x4){0.f,0.f,0.f,0.f};
    for (int kt = 0; kt < 4; ++kt)
#pragma unroll
      for (int mt = 0; mt < 4; ++mt) {
        short8 h = *(const short8*)(hidS + (mt * 16 + n16) * 136 + kt * 32 + kb);
        acc2[mt] = MFMA16(h, w2f[kt], acc2[mt]);
      }
#pragma unroll
    for (int mt = 0; mt < 4; ++mt) {
      int item = mt * 4 + q;  // rows = item*4+f, f=reg
      float g = 0.f;
#pragma unroll
      for (int r = 0; r < 4; ++r) g += lrelu(acc2[mt][r] + b2v);
      int a = item * 136 + col;  // unique (item,col) per lane
      featB[a] = f2bf(bflo((unsigned)featB[a]) + (float)refcntL[item] * g);
    }
    __syncthreads();
  }

  // ---------------- Phase D: inter_items (featB IS the A operand) ----------------
  {
    short8 w1f[4], w2f[4];
#pragma unroll
    for (int kt = 0; kt < 4; ++kt) {
      w1f[kt] = load_bfrag(i2iW1, 128, kt * 32 + kb, col);
      w2f[kt] = load_bfrag(i2iW2, 128, kt * 32 + kb, col);
    }
    const f32x4 b1q = *(const f32x4*)(i2ib1 + wid * 16 + q * 4);
    const float b2v = i2ib2[col];

    for (int u = 0; u < nvs; ++u) {
      const int iv = oiL[vslL[u]];
      f32x4 acc = (f32x4){0.f,0.f,0.f,0.f};
      for (int kt = 0; kt < 4; ++kt) {
        short8 x = *(const short8*)(featB + n16 * 136 + kt * 32 + kb);
        acc = MFMA16(w1f[kt], x, acc);
      }
      {
        float h0 = lrelu(acc[0] + b1q[0]), h1 = lrelu(acc[1] + b1q[1]);
        float h2 = lrelu(acc[2] + b1q[2]), h3 = lrelu(acc[3] + b1q[3]);
        uint2 pk; pk.x = pk2(h0, h1); pk.y = pk2(h2, h3);
        *(uint2*)(hidS + n16 * 136 + wid * 16 + q * 4) = pk;
      }
      __syncthreads();
      f32x4 acc2 = (f32x4){0.f,0.f,0.f,0.f};
      for (int kt = 0; kt < 4; ++kt) {
        short8 h = *(const short8*)(hidS + n16 * 136 + kt * 32 + kb);
        acc2 = MFMA16(h, w2f[kt], acc2);
      }
      // msgs summed per item with weight = (item==iv) ? 0 : refcnt[item]
      float part = 0.f;
#pragma unroll
      for (int r = 0; r < 4; ++r) {
        int item = q * 4 + r;
        float w = (item == iv) ? 0.0f : (float)refcntL[item];
        part += w * lrelu(acc2[r] + b2v);
      }
      part += __shfl_xor(part, 16);
      part += __shfl_xor(part, 32);
      if (q == 0) {
        int a = iv * 136 + col;
        featB[a] = f2bf(bflo((unsigned)featB[a]) + part);
      }
      __syncthreads();
    }
  }

  // ---------------- Phase E: infer_outfit + score ----------------
  if (tid < 128) {
    float sum = 0.0f;
    for (int u = 0; u < nvs; ++u)
      sum += bflo((unsigned)featB[oiL[vslL[u]] * 136 + tid]);
    float v = sum * o2sW[tid];
#pragma unroll
    for (int off = 1; off < 64; off <<= 1) v += __shfl_xor(v, off);
    if (lane == 0) redE[wid] = v;
  }
  __syncthreads();
  if (tid == 0) {
    float t = redE[0] + redE[1] + o2sb[0];
    out[o] = 1.0f / (1.0f + expf(-t));
  }

  // ---------------- Phase F: com_loss from fp32 facL ----------------
  {
    const int n = tid >> 5, f = (tid >> 3) & 3, g = (tid >> 1) & 3, h = tid & 1;
    const float* pa = facL + n * 528 + f * 132 + h * 64;
    const float* pb = facL + n * 528 + g * 132 + h * 64;
    float dot = 0.0f;
    for (int i = 0; i < 16; ++i) {
      float4 a = *(const float4*)(pa + i * 4);
      float4 b = *(const float4*)(pb + i * 4);
      dot += a.x * b.x + a.y * b.y + a.z * b.z + a.w * b.w;
    }
    dot += __shfl_xor(dot, 1);  // combine k-halves
    float v = dot - ((f == g) ? 1.0f : 0.0f);
    float sq = (h == 0 && oiL[n] != -1) ? v * v : 0.0f;
#pragma unroll
    for (int off = 1; off < 64; off <<= 1) sq += __shfl_xor(sq, off);
    __syncthreads();  // E's redE read complete before overwrite
    if (lane == 0) redE[wid] = sq;
    __syncthreads();
    if (tid == 0) {
      float tot = 0.f;
#pragma unroll
      for (int w = 0; w < 8; ++w) tot += redE[w];
      atomicAdd(out + 2048, tot * (1.0f / 2048.0f));
    }
  }
}

extern "C" void kernel_launch(void* const* d_in, const int* in_sizes, int n_in,
                              void* d_out, int out_size, void* d_ws, size_t ws_size,
                              hipStream_t stream) {
  float* out = (float*)d_out;
  hipLaunchKernelGGL(zero_com, dim3(1), dim3(64), 0, stream, out);
  hipLaunchKernelGGL(mfgn_kernel, dim3(2048), dim3(512), 0, stream,
                     (const int*)d_in[0],
                     (const float*)d_in[1],
                     (const int*)d_in[2],
                     // d_in[3] items_factors unused (overwritten by creat_factors)
                     (const float*)d_in[4], (const float*)d_in[5],
                     (const float*)d_in[6], (const float*)d_in[7],
                     (const float*)d_in[8], (const float*)d_in[9],
                     (const float*)d_in[10], (const float*)d_in[11],
                     (const float*)d_in[12], (const float*)d_in[13],
                     (const float*)d_in[14], (const float*)d_in[15],
                     (const float*)d_in[16], (const float*)d_in[17],
                     (const float*)d_in[18], (const float*)d_in[19],
                     (const float*)d_in[20], (const float*)d_in[21],
                     out);
}

// Round 10
// 345.197 us; speedup vs baseline: 2.8647x; 1.3462x over previous
//
#include <hip/hip_runtime.h>
#include <hip/hip_bf16.h>
#include <math.h>

// MFGN forward, MI355X. One block (512 thr, 8 waves) per outfit.
// fp32 facL state in LDS; bf16 featB state in MFMA A-layout (Phase D destaged);
// separate prod/hid buffers (B: 3 barriers/step).
// NO conditional MFMA tile-skip: R8/R9 lesson — `if (mt<mtn)` around unrolled
// MFMA chains induces 127-151MB scratch spill (conditional acc defs blow the
// register peak past the cap). Unconditional 4-tile loops = R5's spill-free
// dataflow; zero-staged rows are masked in the epilogue (same semantics).

typedef __attribute__((ext_vector_type(8))) short short8;
typedef __attribute__((ext_vector_type(4))) float f32x4;

#define MFMA16(a, b, c) __builtin_amdgcn_mfma_f32_16x16x32_bf16(a, b, c, 0, 0, 0)

__device__ __forceinline__ float lrelu(float x) { return x > 0.0f ? x : 0.01f * x; }

__device__ __forceinline__ ushort f2bf(float f) {
  unsigned u = __builtin_bit_cast(unsigned, f);
  u += 0x7fffu + ((u >> 16) & 1u);  // RNE
  return (ushort)(u >> 16);
}
__device__ __forceinline__ float bflo(unsigned u) {
  return __builtin_bit_cast(float, u << 16);
}
__device__ __forceinline__ unsigned pk2(float a, float b) {
  float2 t; t.x = a; t.y = b;
  __hip_bfloat162 h = __float22bfloat162_rn(t);
  unsigned u;
  __builtin_memcpy(&u, &h, 4);
  return u;
}
__device__ __forceinline__ short8 load_bfrag(const float* __restrict__ W, int ldn,
                                             int kbase, int col) {
  short8 r;
#pragma unroll
  for (int j = 0; j < 8; ++j) r[j] = (short)f2bf(W[(kbase + j) * ldn + col]);
  return r;
}

__global__ void zero_com(float* out) { if (threadIdx.x == 0) out[2048] = 0.0f; }

__global__ __launch_bounds__(512, 4) void mfgn_kernel(
    const int* __restrict__ outfit_items,
    const float* __restrict__ items_feature,
    const int* __restrict__ items_neighbor,
    const float* __restrict__ cfW1, const float* __restrict__ cfb1,
    const float* __restrict__ cfW2, const float* __restrict__ cfb2,
    const float* __restrict__ f2fW1, const float* __restrict__ f2fb1,
    const float* __restrict__ f2fW2, const float* __restrict__ f2fb2,
    const float* __restrict__ f2iW1, const float* __restrict__ f2ib1,
    const float* __restrict__ f2iW2, const float* __restrict__ f2ib2,
    const float* __restrict__ i2iW1, const float* __restrict__ i2ib1,
    const float* __restrict__ i2iW2, const float* __restrict__ i2ib2,
    const float* __restrict__ o2sW, const float* __restrict__ o2sb,
    float* __restrict__ out)
{
  __shared__ float facL[16 * 528];                                 // 33792 B fp32 state
  __shared__ ushort prodS[64 * 136] __attribute__((aligned(16)));  // 17408 B bf16 A-staging
  __shared__ ushort hidS[64 * 136] __attribute__((aligned(16)));   // 17408 B bf16 hidden
  __shared__ ushort featB[16 * 136] __attribute__((aligned(16)));  //  4352 B bf16 feat state
  __shared__ float redE[8];
  __shared__ int oiL[16];
  __shared__ int clAll[256];
  __shared__ int ncAll[16];
  __shared__ int vslL[16];
  __shared__ int refcntL[16];
  __shared__ int nvsL;

  const int o = blockIdx.x;
  const int tid = (int)threadIdx.x;
  const int lane = tid & 63;
  const int wid = tid >> 6;        // wave owns output cols wid*16..+15
  const int n16 = lane & 15;
  const int q = lane >> 4;
  const int kb = q * 8;
  const int col = wid * 16 + n16;

  // ---------------- load inputs ----------------
  if (tid < 16) oiL[tid] = outfit_items[o * 16 + tid];
  {
    const int n = tid >> 5, d0 = (tid & 31) * 4;
    float4 v = *(const float4*)(items_feature + o * 2048 + tid * 4);
    uint2 pk; pk.x = pk2(v.x, v.y); pk.y = pk2(v.z, v.w);
    *(uint2*)(featB + n * 136 + d0) = pk;
  }
  if (tid == 0) {
    int cnt = 0;
    for (int s = 0; s < 16; ++s) refcntL[s] = 0;
    for (int s = 0; s < 16; ++s) {
      int v = oiL[s];
      if (v != -1) { vslL[cnt++] = s; refcntL[v]++; }
    }
    nvsL = cnt;
  }
  for (int s = wid; s < 16; s += 8) {
    const int iv = outfit_items[o * 16 + s];
    if (iv == -1) { if (lane == 0) ncAll[s] = 0; continue; }
    int cand = -1;
    if (lane < 24) cand = (lane < 16) ? outfit_items[o * 16 + lane]
                                      : items_neighbor[o * 128 + iv * 8 + (lane - 16)];
    bool ok = (lane < 24) && (cand != -1) && (cand != iv);
    unsigned long long bm = __ballot(ok);
    if (ok) clAll[s * 16 + __popcll(bm & ((1ull << lane) - 1ull))] = cand;
    if (lane == 0) ncAll[s] = (int)__popcll(bm);
  }
  __syncthreads();
  const int nvs = nvsL;

  // ---------------- Phase A: creat_factors ----------------
  {
    const int f = wid & 3, half = wid >> 2;
    short8 wA[2][4];
#pragma unroll
    for (int etl = 0; etl < 2; ++etl)
#pragma unroll
      for (int kt = 0; kt < 4; ++kt)
        wA[etl][kt] = load_bfrag(cfW1 + f * 8192, 64, kt * 32 + kb, (half * 2 + etl) * 16 + n16);
    f32x4 acc[2];
    acc[0] = (f32x4){0.f,0.f,0.f,0.f}; acc[1] = (f32x4){0.f,0.f,0.f,0.f};
    for (int kt = 0; kt < 4; ++kt) {
      short8 x = *(const short8*)(featB + n16 * 136 + kt * 32 + kb);
      acc[0] = MFMA16(wA[0][kt], x, acc[0]);
      acc[1] = MFMA16(wA[1][kt], x, acc[1]);
    }
#pragma unroll
    for (int etl = 0; etl < 2; ++etl) {
      f32x4 b1q = *(const f32x4*)(cfb1 + f * 64 + (half * 2 + etl) * 16 + q * 4);
      float h0 = lrelu(acc[etl][0] + b1q[0]), h1 = lrelu(acc[etl][1] + b1q[1]);
      float h2 = lrelu(acc[etl][2] + b1q[2]), h3 = lrelu(acc[etl][3] + b1q[3]);
      uint2 pk; pk.x = pk2(h0, h1); pk.y = pk2(h2, h3);
      *(uint2*)(hidS + (f * 16 + n16) * 136 + (half * 2 + etl) * 16 + q * 4) = pk;
    }
    __syncthreads();
    short8 wB[4][2];
#pragma unroll
    for (int ctl = 0; ctl < 4; ++ctl)
#pragma unroll
      for (int kt = 0; kt < 2; ++kt)
        wB[ctl][kt] = load_bfrag(cfW2 + f * 8192, 128, kt * 32 + kb, half * 64 + ctl * 16 + n16);
    f32x4 acc2[4];
#pragma unroll
    for (int ctl = 0; ctl < 4; ++ctl) acc2[ctl] = (f32x4){0.f,0.f,0.f,0.f};
    for (int kt = 0; kt < 2; ++kt) {
      short8 h = *(const short8*)(hidS + (f * 16 + n16) * 136 + kt * 32 + kb);
#pragma unroll
      for (int ctl = 0; ctl < 4; ++ctl) acc2[ctl] = MFMA16(h, wB[ctl][kt], acc2[ctl]);
    }
#pragma unroll
    for (int ctl = 0; ctl < 4; ++ctl) {
      int c = half * 64 + ctl * 16 + n16;
      float b2 = cfb2[f * 128 + c];
#pragma unroll
      for (int r = 0; r < 4; ++r)
        facL[(q * 4 + r) * 528 + f * 132 + c] = lrelu(acc2[ctl][r] + b2);
    }
    __syncthreads();
  }

  // ---------------- Phase B: inter_factors (fp32 facL state) ----------------
  {
    short8 w1f[4], w2f[4];
#pragma unroll
    for (int kt = 0; kt < 4; ++kt) {
      w1f[kt] = load_bfrag(f2fW1, 128, kt * 32 + kb, col);
      w2f[kt] = load_bfrag(f2fW2, 128, kt * 32 + kb, col);
    }
    const f32x4 b1q = *(const f32x4*)(f2fb1 + wid * 16 + q * 4);
    const float b2v = f2fb2[col];
    const int rS = tid >> 3, kcS = tid & 7;   // staging: row, 16-value k-chunk
    const int fS = rS & 3, ciS = rS >> 2;
    const int k0 = kcS * 16;

    for (int s = 0; s < 16; ++s) {
      const int iv = oiL[s];
      if (iv == -1) continue;
      const int nc = ncAll[s];
      // stage prod[r=ci*4+f][k] = bf16(fac[iv][f][k] * fac[cand][f][k])
      if (ciS < nc) {
        const int cit = clAll[s * 16 + ciS];
        const float* tp = facL + iv * 528 + fS * 132;
        const float* cp = facL + cit * 528 + fS * 132;
#pragma unroll
        for (int i2 = 0; i2 < 2; ++i2) {
          const int k = k0 + i2 * 8;
          float4 a0 = *(const float4*)(tp + k), a1 = *(const float4*)(tp + k + 4);
          float4 c0 = *(const float4*)(cp + k), c1 = *(const float4*)(cp + k + 4);
          uint4 u;
          u.x = pk2(a0.x * c0.x, a0.y * c0.y); u.y = pk2(a0.z * c0.z, a0.w * c0.w);
          u.z = pk2(a1.x * c1.x, a1.y * c1.y); u.w = pk2(a1.z * c1.z, a1.w * c1.w);
          *(uint4*)(prodS + rS * 136 + k) = u;
        }
      } else {
        uint4 z; z.x = z.y = z.z = z.w = 0;
        *(uint4*)(prodS + rS * 136 + k0) = z;
        *(uint4*)(prodS + rS * 136 + k0 + 8) = z;
      }
      __syncthreads();  // [b1] products ready
      // L1 swapped: lane -> H[row=mt*16+n16][e=wid*16+q*4+reg]; write hidS (own slice)
      f32x4 acc[4];
#pragma unroll
      for (int mt = 0; mt < 4; ++mt) acc[mt] = (f32x4){0.f,0.f,0.f,0.f};
      for (int kt = 0; kt < 4; ++kt)
#pragma unroll
        for (int mt = 0; mt < 4; ++mt) {
          short8 x = *(const short8*)(prodS + (mt * 16 + n16) * 136 + kt * 32 + kb);
          acc[mt] = MFMA16(w1f[kt], x, acc[mt]);
        }
#pragma unroll
      for (int mt = 0; mt < 4; ++mt) {
        float h0 = lrelu(acc[mt][0] + b1q[0]), h1 = lrelu(acc[mt][1] + b1q[1]);
        float h2 = lrelu(acc[mt][2] + b1q[2]), h3 = lrelu(acc[mt][3] + b1q[3]);
        uint2 pk; pk.x = pk2(h0, h1); pk.y = pk2(h2, h3);
        *(uint2*)(hidS + (mt * 16 + n16) * 136 + wid * 16 + q * 4) = pk;
      }
      __syncthreads();  // [b2] hid ready
      // L2 normal: lane -> Y[r=mt*16+q*4+reg][c=col]
      f32x4 acc2[4];
#pragma unroll
      for (int mt = 0; mt < 4; ++mt) acc2[mt] = (f32x4){0.f,0.f,0.f,0.f};
      for (int kt = 0; kt < 4; ++kt)
#pragma unroll
        for (int mt = 0; mt < 4; ++mt) {
          short8 h = *(const short8*)(hidS + (mt * 16 + n16) * 136 + kt * 32 + kb);
          acc2[mt] = MFMA16(h, w2f[kt], acc2[mt]);
        }
      // epilogue: rows ci*4+f (f=reg); mask ci=mt*4+q<nc; sum over ci
      float part[4] = {0.f, 0.f, 0.f, 0.f};
#pragma unroll
      for (int mt = 0; mt < 4; ++mt) {
        bool act = (mt * 4 + q) < nc;
        if (act)
#pragma unroll
          for (int r = 0; r < 4; ++r) part[r] += lrelu(acc2[mt][r] + b2v);
      }
#pragma unroll
      for (int r = 0; r < 4; ++r) {
        float v = part[r];
        v += __shfl_xor(v, 16);
        v += __shfl_xor(v, 32);
        part[r] = v;
      }
      if (q == 0) {  // wave owns cols exclusively -> plain fp32 +=
#pragma unroll
        for (int r = 0; r < 4; ++r)
          facL[iv * 528 + r * 132 + col] += part[r];
      }
      __syncthreads();  // [b3] facL updated for next step's stage
    }
  }

  // ---------------- Phase C: infer_items ----------------
  {
    short8 w1f[4], w2f[4];
#pragma unroll
    for (int kt = 0; kt < 4; ++kt) {
      w1f[kt] = load_bfrag(f2iW1, 128, kt * 32 + kb, col);
      w2f[kt] = load_bfrag(f2iW2, 128, kt * 32 + kb, col);
    }
    const f32x4 b1q = *(const f32x4*)(f2ib1 + wid * 16 + q * 4);
    const float b2v = f2ib2[col];
    // stage prod[r=item*4+f][k] = bf16(fac[item][f][k])
    {
      const int r = tid >> 3, kc = tid & 7, k0 = kc * 16;
      const int f = r & 3, item = r >> 2;
      const float* sp = facL + item * 528 + f * 132;
#pragma unroll
      for (int i2 = 0; i2 < 2; ++i2) {
        const int k = k0 + i2 * 8;
        float4 a0 = *(const float4*)(sp + k), a1 = *(const float4*)(sp + k + 4);
        uint4 u;
        u.x = pk2(a0.x, a0.y); u.y = pk2(a0.z, a0.w);
        u.z = pk2(a1.x, a1.y); u.w = pk2(a1.z, a1.w);
        *(uint4*)(prodS + r * 136 + k) = u;
      }
    }
    __syncthreads();
    f32x4 acc[4];
#pragma unroll
    for (int mt = 0; mt < 4; ++mt) acc[mt] = (f32x4){0.f,0.f,0.f,0.f};
    for (int kt = 0; kt < 4; ++kt)
#pragma unroll
      for (int mt = 0; mt < 4; ++mt) {
        short8 x = *(const short8*)(prodS + (mt * 16 + n16) * 136 + kt * 32 + kb);
        acc[mt] = MFMA16(w1f[kt], x, acc[mt]);
      }
#pragma unroll
    for (int mt = 0; mt < 4; ++mt) {
      float h0 = lrelu(acc[mt][0] + b1q[0]), h1 = lrelu(acc[mt][1] + b1q[1]);
      float h2 = lrelu(acc[mt][2] + b1q[2]), h3 = lrelu(acc[mt][3] + b1q[3]);
      uint2 pk; pk.x = pk2(h0, h1); pk.y = pk2(h2, h3);
      *(uint2*)(hidS + (mt * 16 + n16) * 136 + wid * 16 + q * 4) = pk;
    }
    __syncthreads();
    f32x4 acc2[4];
#pragma unroll
    for (int mt = 0; mt < 4; ++mt) acc2[mt] = (f32x4){0.f,0.f,0.f,0.f};
    for (int kt = 0; kt < 4; ++kt)
#pragma unroll
      for (int mt = 0; mt < 4; ++mt) {
        short8 h = *(const short8*)(hidS + (mt * 16 + n16) * 136 + kt * 32 + kb);
        acc2[mt] = MFMA16(h, w2f[kt], acc2[mt]);
      }
#pragma unroll
    for (int mt = 0; mt < 4; ++mt) {
      int item = mt * 4 + q;  // rows = item*4+f, f=reg
      float g = 0.f;
#pragma unroll
      for (int r = 0; r < 4; ++r) g += lrelu(acc2[mt][r] + b2v);
      int a = item * 136 + col;  // unique (item,col) per lane
      featB[a] = f2bf(bflo((unsigned)featB[a]) + (float)refcntL[item] * g);
    }
    __syncthreads();
  }

  // ---------------- Phase D: inter_items (featB IS the A operand) ----------------
  {
    short8 w1f[4], w2f[4];
#pragma unroll
    for (int kt = 0; kt < 4; ++kt) {
      w1f[kt] = load_bfrag(i2iW1, 128, kt * 32 + kb, col);
      w2f[kt] = load_bfrag(i2iW2, 128, kt * 32 + kb, col);
    }
    const f32x4 b1q = *(const f32x4*)(i2ib1 + wid * 16 + q * 4);
    const float b2v = i2ib2[col];

    for (int u = 0; u < nvs; ++u) {
      const int iv = oiL[vslL[u]];
      f32x4 acc = (f32x4){0.f,0.f,0.f,0.f};
      for (int kt = 0; kt < 4; ++kt) {
        short8 x = *(const short8*)(featB + n16 * 136 + kt * 32 + kb);
        acc = MFMA16(w1f[kt], x, acc);
      }
      {
        float h0 = lrelu(acc[0] + b1q[0]), h1 = lrelu(acc[1] + b1q[1]);
        float h2 = lrelu(acc[2] + b1q[2]), h3 = lrelu(acc[3] + b1q[3]);
        uint2 pk; pk.x = pk2(h0, h1); pk.y = pk2(h2, h3);
        *(uint2*)(hidS + n16 * 136 + wid * 16 + q * 4) = pk;
      }
      __syncthreads();
      f32x4 acc2 = (f32x4){0.f,0.f,0.f,0.f};
      for (int kt = 0; kt < 4; ++kt) {
        short8 h = *(const short8*)(hidS + n16 * 136 + kt * 32 + kb);
        acc2 = MFMA16(h, w2f[kt], acc2);
      }
      // msgs summed per item with weight = (item==iv) ? 0 : refcnt[item]
      float part = 0.f;
#pragma unroll
      for (int r = 0; r < 4; ++r) {
        int item = q * 4 + r;
        float w = (item == iv) ? 0.0f : (float)refcntL[item];
        part += w * lrelu(acc2[r] + b2v);
      }
      part += __shfl_xor(part, 16);
      part += __shfl_xor(part, 32);
      if (q == 0) {
        int a = iv * 136 + col;
        featB[a] = f2bf(bflo((unsigned)featB[a]) + part);
      }
      __syncthreads();
    }
  }

  // ---------------- Phase E: infer_outfit + score ----------------
  if (tid < 128) {
    float sum = 0.0f;
    for (int u = 0; u < nvs; ++u)
      sum += bflo((unsigned)featB[oiL[vslL[u]] * 136 + tid]);
    float v = sum * o2sW[tid];
#pragma unroll
    for (int off = 1; off < 64; off <<= 1) v += __shfl_xor(v, off);
    if (lane == 0) redE[wid] = v;
  }
  __syncthreads();
  if (tid == 0) {
    float t = redE[0] + redE[1] + o2sb[0];
    out[o] = 1.0f / (1.0f + expf(-t));
  }

  // ---------------- Phase F: com_loss from fp32 facL ----------------
  {
    const int n = tid >> 5, f = (tid >> 3) & 3, g = (tid >> 1) & 3, h = tid & 1;
    const float* pa = facL + n * 528 + f * 132 + h * 64;
    const float* pb = facL + n * 528 + g * 132 + h * 64;
    float dot = 0.0f;
    for (int i = 0; i < 16; ++i) {
      float4 a = *(const float4*)(pa + i * 4);
      float4 b = *(const float4*)(pb + i * 4);
      dot += a.x * b.x + a.y * b.y + a.z * b.z + a.w * b.w;
    }
    dot += __shfl_xor(dot, 1);  // combine k-halves
    float v = dot - ((f == g) ? 1.0f : 0.0f);
    float sq = (h == 0 && oiL[n] != -1) ? v * v : 0.0f;
#pragma unroll
    for (int off = 1; off < 64; off <<= 1) sq += __shfl_xor(sq, off);
    __syncthreads();  // E's redE read complete before overwrite
    if (lane == 0) redE[wid] = sq;
    __syncthreads();
    if (tid == 0) {
      float tot = 0.f;
#pragma unroll
      for (int w = 0; w < 8; ++w) tot += redE[w];
      atomicAdd(out + 2048, tot * (1.0f / 2048.0f));
    }
  }
}

extern "C" void kernel_launch(void* const* d_in, const int* in_sizes, int n_in,
                              void* d_out, int out_size, void* d_ws, size_t ws_size,
                              hipStream_t stream) {
  float* out = (float*)d_out;
  hipLaunchKernelGGL(zero_com, dim3(1), dim3(64), 0, stream, out);
  hipLaunchKernelGGL(mfgn_kernel, dim3(2048), dim3(512), 0, stream,
                     (const int*)d_in[0],
                     (const float*)d_in[1],
                     (const int*)d_in[2],
                     // d_in[3] items_factors unused (overwritten by creat_factors)
                     (const float*)d_in[4], (const float*)d_in[5],
                     (const float*)d_in[6], (const float*)d_in[7],
                     (const float*)d_in[8], (const float*)d_in[9],
                     (const float*)d_in[10], (const float*)d_in[11],
                     (const float*)d_in[12], (const float*)d_in[13],
                     (const float*)d_in[14], (const float*)d_in[15],
                     (const float*)d_in[16], (const float*)d_in[17],
                     (const float*)d_in[18], (const float*)d_in[19],
                     (const float*)d_in[20], (const float*)d_in[21],
                     out);
}